// Round 1
// baseline (1184.356 us; speedup 1.0000x reference)
//
#include <hip/hip_runtime.h>
#include <cstddef>

// Sinkhorn matcher: B=32, N=4096, C=558 (+1 dustbin col = M=559), 5 iters, T=1.
// Linear-domain formulation: K = exp(aug); u = mu/(K v); v = nu/(K^T u).
// One fused pass per iteration reads scores once, computes u (row LSE in linear
// domain) and accumulates column sums (K^T u) via register accumulators +
// global fp32 atomics into a tiny B x 559 buffer.

namespace {
constexpr int B_ = 32, N_ = 4096, C_ = 558, M_ = 559, MP_ = 560;

// workspace layout (in floats)
constexpr size_t U_OFF = 0;                              // u: B*N
constexpr size_t V_OFF = (size_t)B_ * N_;                // v: B*MP (padded stride 560)
constexpr size_t A_OFF = V_OFF + (size_t)B_ * MP_;       // acc: B*MP
constexpr size_t I_OFF = A_OFF + (size_t)B_ * MP_;       // invnv: B

// output layout (floats), concatenated in reference return order
constexpr size_t FULL_OFF = 0;                                   // B*N*559
constexpr size_t SOFT_OFF = (size_t)B_ * N_ * M_;                // B*N*558
constexpr size_t HARD_OFF = SOFT_OFF + (size_t)B_ * N_ * C_;     // B*N
constexpr size_t DUST_OFF = HARD_OFF + (size_t)B_ * N_;          // B*N
} // namespace

// Per-batch: count visible, init v=1 (log_v=0), zero acc.
__global__ void k_init(const int* __restrict__ vm, float* __restrict__ ws) {
    const int b = blockIdx.x;
    const int tid = threadIdx.x;
    __shared__ int red[256];
    int s = 0;
    for (int n = tid; n < N_; n += 256) s += (vm[(size_t)b * N_ + n] != 0);
    red[tid] = s;
    __syncthreads();
    for (int off = 128; off > 0; off >>= 1) {
        if (tid < off) red[tid] += red[tid + off];
        __syncthreads();
    }
    if (tid == 0) ws[I_OFF + b] = 1.0f / (float)red[0];
    for (int c = tid; c < MP_; c += 256) {
        ws[V_OFF + (size_t)b * MP_ + c] = 1.0f;
        ws[A_OFF + (size_t)b * MP_ + c] = 0.0f;
    }
}

// One Sinkhorn iteration (row half + column-sum accumulation).
// Grid: (32 chunks, 32 batches), block 256 = 4 waves, wave handles 32 rows.
__global__ __launch_bounds__(256) void k_row(const float* __restrict__ sc,
                                             const int* __restrict__ vm,
                                             const float* __restrict__ dustp,
                                             float* __restrict__ ws) {
    const int b = blockIdx.y;
    const int chunk = blockIdx.x;
    const int wave = threadIdx.x >> 6;
    const int lane = threadIdx.x & 63;

    const float dustE = expf(dustp[0]);        // T = 1
    const float invnv = ws[I_OFF + b];
    const float* __restrict__ vrow = ws + V_OFF + (size_t)b * MP_;
    float* __restrict__ acc = ws + A_OFF + (size_t)b * MP_;

    // v fragment in registers: c = 128k + 2*lane (k<4), tail c = 512+lane
    float2 v2[4];
#pragma unroll
    for (int k = 0; k < 4; ++k)
        v2[k] = *(const float2*)(vrow + k * 128 + 2 * lane);
    float vt = 0.0f;
    if (lane < 46) vt = vrow[512 + lane];
    else if (lane == 46) vt = vrow[558];

    float2 a2[4] = {{0.f, 0.f}, {0.f, 0.f}, {0.f, 0.f}, {0.f, 0.f}};
    float at = 0.0f;

    const int row0 = chunk * 128 + wave * 32;
    for (int r = 0; r < 32; ++r) {
        const int n = row0 + r;
        const float* __restrict__ srow = sc + (size_t)(b * N_ + n) * C_;

        float2 e2[4];
#pragma unroll
        for (int k = 0; k < 4; ++k) {
            float2 x = *(const float2*)(srow + k * 128 + 2 * lane);
            e2[k].x = expf(x.x);
            e2[k].y = expf(x.y);
        }
        float et = 0.0f;
        if (lane < 46) et = expf(srow[512 + lane]);
        else if (lane == 46) et = dustE;

        float s = et * vt;
#pragma unroll
        for (int k = 0; k < 4; ++k)
            s += e2[k].x * v2[k].x + e2[k].y * v2[k].y;
#pragma unroll
        for (int m = 1; m < 64; m <<= 1) s += __shfl_xor(s, m, 64);

        const int vis = vm[(size_t)b * N_ + n];
        const float u = vis ? (invnv / s) : 0.0f;
        if (lane == 0) ws[U_OFF + (size_t)b * N_ + n] = u;

#pragma unroll
        for (int k = 0; k < 4; ++k) {
            a2[k].x += e2[k].x * u;
            a2[k].y += e2[k].y * u;
        }
        at += et * u;
    }

    // flush column partials
#pragma unroll
    for (int k = 0; k < 4; ++k) {
        atomicAdd(&acc[k * 128 + 2 * lane], a2[k].x);
        atomicAdd(&acc[k * 128 + 2 * lane + 1], a2[k].y);
    }
    if (lane <= 46) atomicAdd(&acc[512 + lane], at);  // lane 46 -> c=558
}

// v = nu / colsum; re-zero acc for next iteration.
__global__ void k_vupd(float* __restrict__ ws) {
    const int b = blockIdx.x;
    const float nu = 1.0f / 559.0f;
    for (int c = threadIdx.x; c < M_; c += 256) {
        const float a = ws[A_OFF + (size_t)b * MP_ + c];
        ws[V_OFF + (size_t)b * MP_ + c] = nu / a;
        ws[A_OFF + (size_t)b * MP_ + c] = 0.0f;
    }
}

// Final: P = exp(aug)*u*v; write full, soft, hard (argmax, first-index ties),
// dustbin. Same row/lane mapping as k_row.
__global__ __launch_bounds__(256) void k_final(const float* __restrict__ sc,
                                               const float* __restrict__ dustp,
                                               const float* __restrict__ ws,
                                               float* __restrict__ out) {
    const int b = blockIdx.y;
    const int chunk = blockIdx.x;
    const int wave = threadIdx.x >> 6;
    const int lane = threadIdx.x & 63;

    const float dustE = expf(dustp[0]);
    const float* __restrict__ vrow = ws + V_OFF + (size_t)b * MP_;

    float2 v2[4];
#pragma unroll
    for (int k = 0; k < 4; ++k)
        v2[k] = *(const float2*)(vrow + k * 128 + 2 * lane);
    float vt = 0.0f;
    if (lane < 46) vt = vrow[512 + lane];
    else if (lane == 46) vt = vrow[558];

    const int row0 = chunk * 128 + wave * 32;
    for (int r = 0; r < 32; ++r) {
        const int n = row0 + r;
        const float* __restrict__ srow = sc + (size_t)(b * N_ + n) * C_;
        const float u = ws[U_OFF + (size_t)b * N_ + n];  // broadcast load

        float2 e2[4];
#pragma unroll
        for (int k = 0; k < 4; ++k) {
            float2 x = *(const float2*)(srow + k * 128 + 2 * lane);
            e2[k].x = expf(x.x);
            e2[k].y = expf(x.y);
        }
        float et = 0.0f;
        if (lane < 46) et = expf(srow[512 + lane]);
        else if (lane == 46) et = dustE;

        float2 p2[4];
#pragma unroll
        for (int k = 0; k < 4; ++k) {
            p2[k].x = e2[k].x * u * v2[k].x;
            p2[k].y = e2[k].y * u * v2[k].y;
        }
        const float pt = et * u * vt;  // tail soft value, or dustbin for lane 46

        // full (row stride 559, odd -> scalar dword stores, coalesced)
        float* __restrict__ fr = out + FULL_OFF + (size_t)(b * N_ + n) * M_;
#pragma unroll
        for (int k = 0; k < 4; ++k) {
            fr[k * 128 + 2 * lane] = p2[k].x;
            fr[k * 128 + 2 * lane + 1] = p2[k].y;
        }
        if (lane <= 46) fr[512 + lane] = pt;  // lane 46 writes c=558 (dustbin)

        // soft (row stride 558, even -> float2 stores are 8B-aligned)
        float* __restrict__ so = out + SOFT_OFF + (size_t)(b * N_ + n) * C_;
#pragma unroll
        for (int k = 0; k < 4; ++k)
            *(float2*)(so + k * 128 + 2 * lane) = p2[k];
        if (lane < 46) so[512 + lane] = pt;

        // dustbin weight
        if (lane == 46) out[DUST_OFF + (size_t)b * N_ + n] = pt;

        // argmax over c < 558, ties -> lowest index (np semantics)
        float best = -1.0f;
        int bidx = 0x7fffffff;
#pragma unroll
        for (int k = 0; k < 4; ++k) {
            const int c = k * 128 + 2 * lane;
            if (p2[k].x > best) { best = p2[k].x; bidx = c; }
            if (p2[k].y > best) { best = p2[k].y; bidx = c + 1; }
        }
        if (lane < 46 && pt > best) { best = pt; bidx = 512 + lane; }
#pragma unroll
        for (int m = 1; m < 64; m <<= 1) {
            const float ov = __shfl_xor(best, m, 64);
            const int oi = __shfl_xor(bidx, m, 64);
            if (ov > best || (ov == best && oi < bidx)) { best = ov; bidx = oi; }
        }
        if (lane == 0) out[HARD_OFF + (size_t)b * N_ + n] = (float)bidx;
    }
}

extern "C" void kernel_launch(void* const* d_in, const int* in_sizes, int n_in,
                              void* d_out, int out_size, void* d_ws, size_t ws_size,
                              hipStream_t stream) {
    const float* sc = (const float*)d_in[0];
    const int* vm = (const int*)d_in[1];
    const float* dustp = (const float*)d_in[2];
    float* out = (float*)d_out;
    float* ws = (float*)d_ws;

    k_init<<<B_, 256, 0, stream>>>(vm, ws);
    for (int it = 0; it < 5; ++it) {
        k_row<<<dim3(32, B_), 256, 0, stream>>>(sc, vm, dustp, ws);
        k_vupd<<<B_, 256, 0, stream>>>(ws);
    }
    k_final<<<dim3(32, B_), 256, 0, stream>>>(sc, dustp, ws, out);
}